// Round 12
// baseline (564.369 us; speedup 1.0000x reference)
//
#include <hip/hip_runtime.h>
#include <hip/hip_bf16.h>
#include <hip/hip_fp16.h>

#define NPTS 4096
#define KNB  20
#define EPSB 1e-5f

typedef _Float16 half8  __attribute__((ext_vector_type(8)));
typedef _Float16 half2v __attribute__((ext_vector_type(2)));
typedef float    f32x4  __attribute__((ext_vector_type(4)));
typedef unsigned long long u64;

__device__ __forceinline__ f32x4 mfma16(half8 a, half8 b, f32x4 c){
  return __builtin_amdgcn_mfma_f32_16x16x32_f16(a, b, c, 0, 0, 0);
}

// A fragment from LDS, row-major [rows][C] fp16, XOR-swizzled by (row&7)<<3 elements.
__device__ __forceinline__ half8 loadA_lds(const _Float16* buf, int C, int mt, int ks, int lane){
  int row = mt*16 + (lane & 15);
  int k0  = ks*32 + (lane >> 4)*8;
  int e   = (row*C + k0) ^ ((row & 7) << 3);
  return *reinterpret_cast<const half8*>(&buf[e]);
}

// B fragment from global, WT is [N_out][K] fp16 (pre-transposed weight)
__device__ __forceinline__ half8 loadB_g(const _Float16* WT, int K, int nt, int ks, int lane){
  int col = nt*16 + (lane & 15);
  int k0  = ks*32 + (lane >> 4)*8;
  return *reinterpret_cast<const half8*>(&WT[col*K + k0]);
}

__device__ __forceinline__ half2v pkmax(half2v a, half2v b){
  return __builtin_elementwise_max(a, b);
}
__device__ __forceinline__ half2v shflx_h2(half2v v, int m){
  int iv = __builtin_bit_cast(int, v);
  iv = __shfl_xor(iv, m);
  return __builtin_bit_cast(half2v, iv);
}
// cvt_pk f32x2 -> f16x2, then packed scale+bias+lrelu (one col => one sc/bs)
__device__ __forceinline__ half2v ep_pk(float a, float b, half2v sc2, half2v bs2){
  half2v v = __builtin_bit_cast(half2v, __builtin_amdgcn_cvt_pkrtz(a, b));
  v = v*sc2 + bs2;
  half2v w = v * (half2v){(_Float16)0.2f, (_Float16)0.2f};
  return pkmax(v, w);
}

// ---------------- KNN ----------------
// 1024 thr = 16 waves, TWO rows per wave (lanes 0-31 row A, 32-63 row B).
// Candidates j = t*32 + (lane&31), t=0..127, streamed from LDS (same-address
// broadcast across halves -> conflict-free). Distance loop: f32 min/max insert
// net (r10). Selection: u32 key = (monotone(b1)&~63)|lane, 5-step butterfly
// within each half (every instr serves 2 rows); winner lane = key&63;
// branchless promote; rare rebuild vs 128-bit removed-t mask.
__global__ __launch_bounds__(1024)
void knn_kernel(const float* __restrict__ x, int* __restrict__ idx_out){
  __shared__ float4 spts[NPTS];           // (x,y,z,0.5*xx) 64KB
  int b  = blockIdx.x >> 7;               // 128 row-blocks per batch
  int r0 = (blockIdx.x & 127) << 5;       // 32 rows per block
  const float* xb = x + (size_t)b*NPTS*3;
  for (int t = threadIdx.x; t < NPTS; t += 1024){
    float px = xb[t*3+0], py = xb[t*3+1], pz = xb[t*3+2];
    spts[t] = make_float4(px, py, pz, 0.5f*(px*px + py*py + pz*pz));
  }
  __syncthreads();
  int wave = threadIdx.x >> 6, lane = threadIdx.x & 63;
  int half = lane >> 5, l31 = lane & 31;
  int i = r0 + wave*2 + half;
  float4 pi = spts[i];
  float b1 = -INFINITY, b2 = -INFINITY, b3 = -INFINITY;
  int   i1 = 0, i2 = 0, i3 = 0;
  #pragma unroll 8
  for (int t = 0; t < 128; ++t){
    int j = (t << 5) + l31;
    float4 q = spts[j];
    float d = pi.x*q.x + pi.y*q.y + pi.z*q.z - pi.w - q.w;   // = -dist^2/2
    bool c1 = d > b1, c2 = d > b2, c3 = d > b3;
    float t2 = fmaxf(b2, fminf(b1, d));
    float t3 = fmaxf(b3, fminf(b2, d));
    i3 = c2 ? i2 : (c3 ? j : i3);
    i2 = c1 ? i1 : (c2 ? j : i2);
    i1 = c1 ? j : i1;
    b1 = fmaxf(b1, d);
    b2 = t2; b3 = t3;
  }
  u64 rem_lo = 0ull, rem_hi = 0ull;       // removed candidate t-bits (t=0..127)
  size_t obase = ((size_t)b*NPTS + i)*KNB;
  #pragma unroll 1
  for (int kk = 0; kk < KNB; ++kk){
    unsigned s = __float_as_uint(b1);
    unsigned key = s ^ ((unsigned)(((int)s) >> 31) | 0x80000000u);
    key = (key & 0xFFFFFFC0u) | (unsigned)lane;    // lane in low bits
    unsigned bv = key;
    #pragma unroll
    for (int m = 1; m <= 16; m <<= 1){     // 5-step max within 32-lane half
      unsigned ov = (unsigned)__shfl_xor((int)bv, m);
      bv = bv > ov ? bv : ov;
    }
    int wl = (int)(bv & 63u);              // winner lane (lane bits embed half)
    int bj = __shfl(i1, wl);
    if (l31 == 0) idx_out[obase + kk] = bj;
    bool iw = (lane == wl);                // exactly one lane per half
    int tt = i1 >> 5;
    u64 bit = 1ull << (tt & 63);
    rem_lo |= (iw && tt < 64) ? bit : 0ull;
    rem_hi |= (iw && tt >= 64) ? bit : 0ull;
    b1 = iw ? b2 : b1;  i1 = iw ? i2 : i1;
    b2 = iw ? b3 : b2;  i2 = iw ? i3 : i2;
    b3 = iw ? -INFINITY : b3;
    if (kk < KNB-1 && __any(b1 == -INFINITY)){
      if (b1 == -INFINITY){               // rare: rebuild top-3 from LDS
        b2 = -INFINITY; b3 = -INFINITY; i1 = 0; i2 = 0; i3 = 0;
        #pragma unroll 8
        for (int t = 0; t < 128; ++t){
          bool rm = (t < 64) ? ((rem_lo >> t) & 1ull) : ((rem_hi >> (t - 64)) & 1ull);
          if (rm) continue;
          int j = (t << 5) + l31;
          float4 q = spts[j];
          float d = pi.x*q.x + pi.y*q.y + pi.z*q.z - pi.w - q.w;
          bool c1 = d > b1, c2 = d > b2, c3 = d > b3;
          float t2 = fmaxf(b2, fminf(b1, d));
          float t3 = fmaxf(b3, fminf(b2, d));
          i3 = c2 ? i2 : (c3 ? j : i3);
          i2 = c1 ? i1 : (c2 ? j : i2);
          i1 = c1 ? j : i1;
          b1 = fmaxf(b1, d);
          b2 = t2; b3 = t3;
        }
      }
    }
  }
}

// ---------------- weight prep ----------------
__global__ __launch_bounds__(256)
void prep_kernel(const float* __restrict__ W2, const float* __restrict__ W3,
                 const float* __restrict__ W4,
                 _Float16* __restrict__ W2T, _Float16* __restrict__ W3T,
                 _Float16* __restrict__ W4T){
  int t = blockIdx.x*256 + threadIdx.x;
  if (t < 4096){ int o=t>>6, k=t&63;                W2T[t] = (_Float16)W2[k*64+o]; }
  else if (t < 12288){ int u=t-4096;  int o=u>>6, k=u&63;   W3T[u] = (_Float16)W3[k*128+o]; }
  else if (t < 45056){ int u=t-12288; int o=u>>7, k=u&127;  W4T[u] = (_Float16)W4[k*256+o]; }
}

__global__ __launch_bounds__(256)
void prep5_kernel(const float* __restrict__ W5, _Float16* __restrict__ W5T){
  __shared__ float tile[32][33];
  int tk = (blockIdx.x & 15) << 5;
  int to = (blockIdx.x >> 4) << 5;
  int lr = threadIdx.x >> 5;
  int lc = threadIdx.x & 31;
  #pragma unroll
  for (int r = 0; r < 32; r += 8)
    tile[lr + r][lc] = W5[(size_t)(tk + lr + r)*1024 + to + lc];
  __syncthreads();
  #pragma unroll
  for (int r = 0; r < 32; r += 8)
    W5T[(size_t)(to + lr + r)*512 + tk + lc] = (_Float16)tile[lc][lr + r];
}

// ---------------- fused edge layers 1-4, packed-f16 epilogues (r10) ----------------
__device__ __forceinline__ void pk_bucket(int mt, bool c1, bool c2, bool c3, half2v m,
                                          half2v& q0, half2v& q1, half2v& q2, half2v& q3){
  const half2v NI = {(_Float16)-INFINITY, (_Float16)-INFINITY};
  if (mt == 0)      q0 = pkmax(q0, m);
  else if (mt == 4) q3 = pkmax(q3, m);
  else if (mt == 1){ q1 = pkmax(q1, c1 ? m : NI); q0 = pkmax(q0, c1 ? NI : m); }
  else if (mt == 2){ q2 = pkmax(q2, c2 ? m : NI); q1 = pkmax(q1, c2 ? NI : m); }
  else             { q3 = pkmax(q3, c3 ? m : NI); q2 = pkmax(q2, c3 ? NI : m); }
}

__device__ __forceinline__ void reduce_write_pk(half2v q0, half2v q1, half2v q2, half2v q3,
                                                _Float16* __restrict__ hc, size_t gp0,
                                                int off, int g, int c){
  q0 = pkmax(q0, shflx_h2(q0,16)); q0 = pkmax(q0, shflx_h2(q0,32));
  q1 = pkmax(q1, shflx_h2(q1,16)); q1 = pkmax(q1, shflx_h2(q1,32));
  q2 = pkmax(q2, shflx_h2(q2,16)); q2 = pkmax(q2, shflx_h2(q2,32));
  q3 = pkmax(q3, shflx_h2(q3,16)); q3 = pkmax(q3, shflx_h2(q3,32));
  half2v v = (g == 0) ? q0 : (g == 1) ? q1 : (g == 2) ? q2 : q3;
  _Float16 r = v.x > v.y ? v.x : v.y;
  hc[(gp0 + g)*512 + off + c] = r;
}

__global__ __launch_bounds__(256)
void edge_kernel(const float* __restrict__ x, const int* __restrict__ knn,
                 const float* __restrict__ W1, const float* __restrict__ g1, const float* __restrict__ b1,
                 const _Float16* __restrict__ W2T, const float* __restrict__ g2, const float* __restrict__ b2,
                 const _Float16* __restrict__ W3T, const float* __restrict__ g3, const float* __restrict__ b3,
                 const _Float16* __restrict__ W4T, const float* __restrict__ g4, const float* __restrict__ b4,
                 _Float16* __restrict__ hc){
  __shared__ __align__(16) char smem[40960];
  _Float16* hb1 = (_Float16*)(smem);             // 80*64*2  = 10240
  _Float16* hb2 = (_Float16*)(smem + 10240);     // 80*64*2  = 10240
  _Float16* hb3 = (_Float16*)(smem + 20480);     // 80*128*2 = 20480
  float*    h0f = (float*)(smem + 20480);        // aliases hb3 head (dead before hb3 written)
  float*    h0c = (float*)(smem + 20480 + 1280);
  const float rs = 1.f / sqrtf(1.f + EPSB);
  const half2v NI = {(_Float16)-INFINITY, (_Float16)-INFINITY};
  int gp0 = blockIdx.x << 2;
  int b   = gp0 >> 12;
  int n0  = gp0 & (NPTS-1);
  const float* xb = x + (size_t)b*NPTS*3;
  int tid = threadIdx.x;
  if (tid < 80){
    int p = tid / 20, k = tid % 20;
    int nb = knn[((size_t)b*NPTS + n0 + p)*KNB + k];
    h0f[tid*4+0] = xb[nb*3+0];
    h0f[tid*4+1] = xb[nb*3+1];
    h0f[tid*4+2] = xb[nb*3+2];
  } else if (tid < 96){
    int u = tid - 80; int p = u >> 2, c = u & 3;
    if (c < 3) h0c[p*4+c] = xb[(n0+p)*3+c];
  }
  __syncthreads();
  int w = tid >> 6, lane = tid & 63, g = lane >> 4, cc = lane & 15;
  bool c1 = (g >= 1), c2 = (g >= 2), c3 = (g >= 3);
  // ---- layer 1: f32 VALU (K=6) ----
  {
    int col = lane;
    float sc = g1[col]*rs, bs = b1[col];
    float w0=W1[col], w1_=W1[64+col], w2_=W1[128+col], w3_=W1[192+col], w4_=W1[256+col], w5_=W1[320+col];
    float cx = h0c[w*4+0], cy = h0c[w*4+1], cz = h0c[w*4+2];
    float m1 = -INFINITY;
    #pragma unroll 5
    for (int k = 0; k < KNB; ++k){
      int r = w*20 + k;
      float a = h0f[r*4+0]*w0 + h0f[r*4+1]*w1_ + h0f[r*4+2]*w2_ + cx*w3_ + cy*w4_ + cz*w5_;
      float vv = a*sc + bs; vv = vv > 0.f ? vv : 0.2f*vv;
      hb1[((r<<6)+col) ^ ((r&7)<<3)] = (_Float16)vv;
      m1 = fmaxf(m1, vv);
    }
    hc[(size_t)(gp0 + w)*512 + col] = (_Float16)m1;
  }
  __syncthreads();
  // ---- layer 2: [80,64]@[64,64]; wave w owns cols w*16..+16 ----
  {
    int colg = (w<<4) + cc;
    float scf = g2[colg]*rs, bsf = b2[colg];
    half2v sc2 = {(_Float16)scf,(_Float16)scf}, bs2 = {(_Float16)bsf,(_Float16)bsf};
    half8 bf0 = loadB_g(W2T, 64, w, 0, lane);
    half8 bf1 = loadB_g(W2T, 64, w, 1, lane);
    half2v q0=NI, q1=NI, q2=NI, q3=NI;
    #pragma unroll
    for (int mt = 0; mt < 5; ++mt){
      f32x4 a = {0.f,0.f,0.f,0.f};
      a = mfma16(loadA_lds(hb1,64,mt,0,lane), bf0, a);
      a = mfma16(loadA_lds(hb1,64,mt,1,lane), bf1, a);
      half2v lo = ep_pk(a[0], a[1], sc2, bs2);
      half2v hi = ep_pk(a[2], a[3], sc2, bs2);
      int r0_ = mt*16 + g*4;
      hb2[((r0_+0)*64+colg) ^ (((r0_+0)&7)<<3)] = lo.x;
      hb2[((r0_+1)*64+colg) ^ (((r0_+1)&7)<<3)] = lo.y;
      hb2[((r0_+2)*64+colg) ^ (((r0_+2)&7)<<3)] = hi.x;
      hb2[((r0_+3)*64+colg) ^ (((r0_+3)&7)<<3)] = hi.y;
      pk_bucket(mt, c1, c2, c3, pkmax(lo,hi), q0, q1, q2, q3);
    }
    reduce_write_pk(q0,q1,q2,q3, hc, gp0, 64 + (w<<4), g, cc);
  }
  __syncthreads();
  // ---- layer 3: [80,64]@[64,128]; wave w owns ntiles 2w,2w+1; A reused ----
  {
    int ntA = (w<<1), ntB = ntA + 1;
    int colA = (ntA<<4) + cc, colB = (ntB<<4) + cc;
    float sAf = g3[colA]*rs, bAf = b3[colA];
    float sBf = g3[colB]*rs, bBf = b3[colB];
    half2v scA2={(_Float16)sAf,(_Float16)sAf}, bsA2={(_Float16)bAf,(_Float16)bAf};
    half2v scB2={(_Float16)sBf,(_Float16)sBf}, bsB2={(_Float16)bBf,(_Float16)bBf};
    half8 bA0 = loadB_g(W3T, 64, ntA, 0, lane);
    half8 bA1 = loadB_g(W3T, 64, ntA, 1, lane);
    half8 bB0 = loadB_g(W3T, 64, ntB, 0, lane);
    half8 bB1 = loadB_g(W3T, 64, ntB, 1, lane);
    half2v qA0=NI,qA1=NI,qA2=NI,qA3=NI, qB0=NI,qB1=NI,qB2=NI,qB3=NI;
    #pragma unroll
    for (int mt = 0; mt < 5; ++mt){
      half8 a0 = loadA_lds(hb2,64,mt,0,lane);
      half8 a1 = loadA_lds(hb2,64,mt,1,lane);
      f32x4 aA = {0.f,0.f,0.f,0.f};
      aA = mfma16(a0, bA0, aA); aA = mfma16(a1, bA1, aA);
      f32x4 aB = {0.f,0.f,0.f,0.f};
      aB = mfma16(a0, bB0, aB); aB = mfma16(a1, bB1, aB);
      half2v loA = ep_pk(aA[0],aA[1],scA2,bsA2);
      half2v hiA = ep_pk(aA[2],aA[3],scA2,bsA2);
      half2v loB = ep_pk(aB[0],aB[1],scB2,bsB2);
      half2v hiB = ep_pk(aB[2],aB[3],scB2,bsB2);
      int r0_ = mt*16 + g*4;
      hb3[((r0_+0)*128+colA) ^ (((r0_+0)&7)<<3)] = loA.x;
      hb3[((r0_+1)*128+colA) ^ (((r0_+1)&7)<<3)] = loA.y;
      hb3[((r0_+2)*128+colA) ^ (((r0_+2)&7)<<3)] = hiA.x;
      hb3[((r0_+3)*128+colA) ^ (((r0_+3)&7)<<3)] = hiA.y;
      hb3[((r0_+0)*128+colB) ^ (((r0_+0)&7)<<3)] = loB.x;
      hb3[((r0_+1)*128+colB) ^ (((r0_+1)&7)<<3)] = loB.y;
      hb3[((r0_+2)*128+colB) ^ (((r0_+2)&7)<<3)] = hiB.x;
      hb3[((r0_+3)*128+colB) ^ (((r0_+3)&7)<<3)] = hiB.y;
      pk_bucket(mt, c1, c2, c3, pkmax(loA,hiA), qA0,qA1,qA2,qA3);
      pk_bucket(mt, c1, c2, c3, pkmax(loB,hiB), qB0,qB1,qB2,qB3);
    }
    reduce_write_pk(qA0,qA1,qA2,qA3, hc, gp0, 128 + (ntA<<4), g, cc);
    reduce_write_pk(qB0,qB1,qB2,qB3, hc, gp0, 128 + (ntB<<4), g, cc);
  }
  __syncthreads();
  // ---- layer 4: [80,128]@[128,256]; pure reg output ----
  #pragma unroll 1
  for (int pass = 0; pass < 2; ++pass){
    int ntA = (pass<<3) + w, ntB = ntA + 4;
    int colA = (ntA<<4) + cc, colB = (ntB<<4) + cc;
    float sAf = g4[colA]*rs, bAf = b4[colA];
    float sBf = g4[colB]*rs, bBf = b4[colB];
    half2v scA2={(_Float16)sAf,(_Float16)sAf}, bsA2={(_Float16)bAf,(_Float16)bAf};
    half2v scB2={(_Float16)sBf,(_Float16)sBf}, bsB2={(_Float16)bBf,(_Float16)bBf};
    half8 bwA[4], bwB[4];
    #pragma unroll
    for (int ks = 0; ks < 4; ++ks){
      bwA[ks] = loadB_g(W4T, 128, ntA, ks, lane);
      bwB[ks] = loadB_g(W4T, 128, ntB, ks, lane);
    }
    half2v qA0=NI,qA1=NI,qA2=NI,qA3=NI, qB0=NI,qB1=NI,qB2=NI,qB3=NI;
    #pragma unroll
    for (int mt = 0; mt < 5; ++mt){
      half8 a[4];
      #pragma unroll
      for (int ks = 0; ks < 4; ++ks) a[ks] = loadA_lds(hb3,128,mt,ks,lane);
      f32x4 aA = {0.f,0.f,0.f,0.f};
      #pragma unroll
      for (int ks = 0; ks < 4; ++ks) aA = mfma16(a[ks], bwA[ks], aA);
      f32x4 aB = {0.f,0.f,0.f,0.f};
      #pragma unroll
      for (int ks = 0; ks < 4; ++ks) aB = mfma16(a[ks], bwB[ks], aB);
      half2v mA = pkmax(ep_pk(aA[0],aA[1],scA2,bsA2), ep_pk(aA[2],aA[3],scA2,bsA2));
      half2v mB = pkmax(ep_pk(aB[0],aB[1],scB2,bsB2), ep_pk(aB[2],aB[3],scB2,bsB2));
      pk_bucket(mt, c1, c2, c3, mA, qA0,qA1,qA2,qA3);
      pk_bucket(mt, c1, c2, c3, mB, qB0,qB1,qB2,qB3);
    }
    reduce_write_pk(qA0,qA1,qA2,qA3, hc, gp0, 256 + (ntA<<4), g, cc);
    reduce_write_pk(qB0,qB1,qB2,qB3, hc, gp0, 256 + (ntB<<4), g, cc);
  }
}

// ---------------- layer 5 GEMM + pooling partials ----------------
__global__ __launch_bounds__(256)
void gemm5_kernel(const _Float16* __restrict__ hc, const _Float16* __restrict__ W5T,
                  const float* __restrict__ g5, const float* __restrict__ b5,
                  float* __restrict__ red){
  __shared__ __align__(16) _Float16 sA[64*512];   // 64KB
  int rowblk = blockIdx.x >> 2;
  int colblk = blockIdx.x & 3;
  int row0 = rowblk << 6;
  #pragma unroll 1
  for (int it = 0; it < 16; ++it){
    int eoff = it*2048 + threadIdx.x*8;
    int row = eoff >> 9;
    int ine = eoff & 511;
    half8 vsrc = *reinterpret_cast<const half8*>(
        &hc[(size_t)(row0 + row)*512 + (ine ^ ((row & 7) << 3))]);
    *reinterpret_cast<half8*>(&sA[(row << 9) + ine]) = vsrc;
  }
  __syncthreads();
  int wave = threadIdx.x >> 6, lane = threadIdx.x & 63;
  f32x4 acc[4][4] = {};
  #pragma unroll 1
  for (int ks = 0; ks < 16; ++ks){
    half8 af[4];
    #pragma unroll
    for (int mt = 0; mt < 4; ++mt) af[mt] = loadA_lds(sA, 512, mt, ks, lane);
    #pragma unroll
    for (int nt = 0; nt < 4; ++nt){
      int ntg = (colblk<<4) + (wave<<2) + nt;
      half8 bf = loadB_g(W5T, 512, ntg, ks, lane);
      #pragma unroll
      for (int mt = 0; mt < 4; ++mt)
        acc[mt][nt] = mfma16(af[mt], bf, acc[mt][nt]);
    }
  }
  int batch = row0 >> 12;
  int chunk = (row0 & (NPTS-1)) >> 6;
  const float rs = 1.f/sqrtf(1.f+EPSB);
  #pragma unroll
  for (int nt = 0; nt < 4; ++nt){
    int ntg = (colblk<<4) + (wave<<2) + nt;
    int colg = (ntg<<4) + (lane & 15);
    float sc = g5[colg]*rs, bs = b5[colg];
    float vmax = -INFINITY, vsum = 0.f;
    #pragma unroll
    for (int mt = 0; mt < 4; ++mt){
      #pragma unroll
      for (int r = 0; r < 4; ++r){
        float vv = acc[mt][nt][r]*sc + bs;
        vv = vv>0.f ? vv : 0.2f*vv;
        vmax = fmaxf(vmax, vv); vsum += vv;
      }
    }
    vmax = fmaxf(vmax, __shfl_xor(vmax, 16)); vsum += __shfl_xor(vsum, 16);
    vmax = fmaxf(vmax, __shfl_xor(vmax, 32)); vsum += __shfl_xor(vsum, 32);
    if ((lane >> 4) == 0){
      size_t base = (size_t)((batch<<6) + chunk)*2048;
      red[base + colg] = vmax;
      red[base + 1024 + colg] = vsum;
    }
  }
}

__global__ __launch_bounds__(256)
void reduce_g_kernel(const float* __restrict__ red, float* __restrict__ g){
  int t = blockIdx.x*256 + threadIdx.x;   // 8192
  int b = t >> 10, col = t & 1023;
  float m = -INFINITY, s = 0.f;
  #pragma unroll 4
  for (int c = 0; c < 64; ++c){
    size_t base = (size_t)((b<<6)+c)*2048;
    m = fmaxf(m, red[base + col]);
    s += red[base + 1024 + col];
  }
  g[(b<<11) + col]        = m;
  g[(b<<11) + 1024 + col] = s * (1.f/4096.f);
}

// ---------------- head MLP: split-K, coalesced o-major loads ----------------
__global__ __launch_bounds__(256)
void fc1_kernel(const float* __restrict__ g, const float* __restrict__ L1,
                const float* __restrict__ g6, const float* __restrict__ b6,
                float* __restrict__ f1){
  __shared__ float part[4][64];
  int b  = blockIdx.x >> 3;
  int og = blockIdx.x & 7;
  int o  = (og << 6) + (threadIdx.x & 63);
  int kg = threadIdx.x >> 6;
  const float* gb = g + (b << 11);
  float acc = 0.f;
  #pragma unroll 8
  for (int k = kg*512; k < kg*512 + 512; ++k) acc += gb[k]*L1[k*512 + o];
  part[kg][threadIdx.x & 63] = acc;
  __syncthreads();
  if (threadIdx.x < 64){
    float s = part[0][threadIdx.x] + part[1][threadIdx.x] + part[2][threadIdx.x] + part[3][threadIdx.x];
    float v = s*(g6[o]/sqrtf(1.f+EPSB)) + b6[o];
    f1[(b<<9) + o] = v > 0.f ? v : 0.2f*v;
  }
}

__global__ __launch_bounds__(256)
void fc2_kernel(const float* __restrict__ f1, const float* __restrict__ L2, const float* __restrict__ L2b,
                const float* __restrict__ g7, const float* __restrict__ b7, float* __restrict__ f2){
  __shared__ float part[4][64];
  int b  = blockIdx.x >> 2;
  int og = blockIdx.x & 3;
  int o  = (og << 6) + (threadIdx.x & 63);
  int kg = threadIdx.x >> 6;
  const float* fb = f1 + (b << 9);
  float acc = 0.f;
  #pragma unroll 8
  for (int k = kg*128; k < kg*128 + 128; ++k) acc += fb[k]*L2[k*256 + o];
  part[kg][threadIdx.x & 63] = acc;
  __syncthreads();
  if (threadIdx.x < 64){
    float s = part[0][threadIdx.x] + part[1][threadIdx.x] + part[2][threadIdx.x] + part[3][threadIdx.x];
    float v = (s + L2b[o])*(g7[o]/sqrtf(1.f+EPSB)) + b7[o];
    f2[(b<<8) + o] = v > 0.f ? v : 0.2f*v;
  }
}

__global__ __launch_bounds__(256)
void fc3_kernel(const float* __restrict__ f2, const float* __restrict__ L3, const float* __restrict__ L3b,
                float* __restrict__ out){
  __shared__ float part[2][128];
  int b  = blockIdx.x;
  int o  = threadIdx.x & 127;
  int kg = threadIdx.x >> 7;
  const float* fb = f2 + (b << 8);
  float acc = 0.f;
  #pragma unroll 8
  for (int k = kg*128; k < kg*128 + 128; ++k) acc += fb[k]*L3[k*128 + o];
  part[kg][o] = acc;
  __syncthreads();
  if (threadIdx.x < 128)
    out[(b<<7) + o] = part[0][o] + part[1][o] + L3b[o];
}

extern "C" void kernel_launch(void* const* d_in, const int* in_sizes, int n_in,
                              void* d_out, int out_size, void* d_ws, size_t ws_size,
                              hipStream_t stream){
  const float* x  = (const float*)d_in[0];
  const float* W1 = (const float*)d_in[1];
  const float* g1 = (const float*)d_in[2];  const float* b1 = (const float*)d_in[3];
  const float* W2 = (const float*)d_in[4];
  const float* g2 = (const float*)d_in[5];  const float* b2 = (const float*)d_in[6];
  const float* W3 = (const float*)d_in[7];
  const float* g3 = (const float*)d_in[8];  const float* b3 = (const float*)d_in[9];
  const float* W4 = (const float*)d_in[10];
  const float* g4 = (const float*)d_in[11]; const float* b4 = (const float*)d_in[12];
  const float* W5 = (const float*)d_in[13];
  const float* g5 = (const float*)d_in[14]; const float* b5 = (const float*)d_in[15];
  const float* L1 = (const float*)d_in[16];
  const float* g6 = (const float*)d_in[17]; const float* b6 = (const float*)d_in[18];
  const float* L2 = (const float*)d_in[19]; const float* L2b = (const float*)d_in[20];
  const float* g7 = (const float*)d_in[21]; const float* b7 = (const float*)d_in[22];
  const float* L3 = (const float*)d_in[23]; const float* L3b = (const float*)d_in[24];

  char* ws = (char*)d_ws;
  int*      idx  = (int*)(ws + 0);                 // 2,621,440 B
  _Float16* hc   = (_Float16*)(ws + 2621440);      // 33,554,432 B
  _Float16* W2T  = (_Float16*)(ws + 36175872);     // 8,192 B
  _Float16* W3T  = (_Float16*)(ws + 36184064);     // 16,384 B
  _Float16* W4T  = (_Float16*)(ws + 36200448);     // 65,536 B
  _Float16* W5T  = (_Float16*)(ws + 36265984);     // 1,048,576 B
  float*    red  = (float*)(ws + 37314560);        // 4,194,304 B
  float*    gbuf = (float*)(ws + 41508864);        // 65,536 B
  float*    f1   = (float*)(ws + 41574400);        // 16,384 B
  float*    f2   = (float*)(ws + 41590784);        // 8,192 B

  knn_kernel<<<1024, 1024, 0, stream>>>(x, idx);
  prep_kernel<<<176, 256, 0, stream>>>(W2, W3, W4, W2T, W3T, W4T);
  prep5_kernel<<<512, 256, 0, stream>>>(W5, W5T);
  edge_kernel<<<8192, 256, 0, stream>>>(x, idx, W1, g1, b1, W2T, g2, b2,
                                        W3T, g3, b3, W4T, g4, b4, hc);
  gemm5_kernel<<<2048, 256, 0, stream>>>(hc, W5T, g5, b5, red);
  reduce_g_kernel<<<32, 256, 0, stream>>>(red, gbuf);
  fc1_kernel<<<64, 256, 0, stream>>>(gbuf, L1, g6, b6, f1);
  fc2_kernel<<<32, 256, 0, stream>>>(f1, L2, L2b, g7, b7, f2);
  fc3_kernel<<<8, 256, 0, stream>>>(f2, L3, L3b, (float*)d_out);
}

// Round 13
// 399.895 us; speedup vs baseline: 1.4113x; 1.4113x over previous
//
#include <hip/hip_runtime.h>
#include <hip/hip_bf16.h>
#include <hip/hip_fp16.h>

#define NPTS 4096
#define KNB  20
#define EPSB 1e-5f

typedef _Float16 half8  __attribute__((ext_vector_type(8)));
typedef _Float16 half2v __attribute__((ext_vector_type(2)));
typedef float    f32x4  __attribute__((ext_vector_type(4)));

__device__ __forceinline__ f32x4 mfma16(half8 a, half8 b, f32x4 c){
  return __builtin_amdgcn_mfma_f32_16x16x32_f16(a, b, c, 0, 0, 0);
}

// A fragment from LDS, row-major [rows][C] fp16, XOR-swizzled by (row&7)<<3 elements.
__device__ __forceinline__ half8 loadA_lds(const _Float16* buf, int C, int mt, int ks, int lane){
  int row = mt*16 + (lane & 15);
  int k0  = ks*32 + (lane >> 4)*8;
  int e   = (row*C + k0) ^ ((row & 7) << 3);
  return *reinterpret_cast<const half8*>(&buf[e]);
}

// B fragment from global, WT is [N_out][K] fp16 (pre-transposed weight)
__device__ __forceinline__ half8 loadB_g(const _Float16* WT, int K, int nt, int ks, int lane){
  int col = nt*16 + (lane & 15);
  int k0  = ks*32 + (lane >> 4)*8;
  return *reinterpret_cast<const half8*>(&WT[col*K + k0]);
}

__device__ __forceinline__ half2v pkmax(half2v a, half2v b){
  return __builtin_elementwise_max(a, b);
}
__device__ __forceinline__ half2v shflx_h2(half2v v, int m){
  int iv = __builtin_bit_cast(int, v);
  iv = __shfl_xor(iv, m);
  return __builtin_bit_cast(half2v, iv);
}
// cvt_pk f32x2 -> f16x2, then packed scale+bias+lrelu (one col => one sc/bs)
__device__ __forceinline__ half2v ep_pk(float a, float b, half2v sc2, half2v bs2){
  half2v v = __builtin_bit_cast(half2v, __builtin_amdgcn_cvt_pkrtz(a, b));
  v = v*sc2 + bs2;
  half2v w = v * (half2v){(_Float16)0.2f, (_Float16)0.2f};
  return pkmax(v, w);
}

// ---------------- KNN ---------------- (r10 structure: 1 row/wave, 2048 blocks)
// spts.w = 0.5*||x||^2; d = dot - hwi - hwj (= -dist^2/2, order-identical).
// Top-3 insert via med3 net: b1'=max(b1,d); b2'=med3(d,b1,b2); b3'=med3(d,b2,b3).
// Selection: u32 key = (monotone(b1)&~63)|lane; 6-step max butterfly; winner
// lane = key&63; branchless promote; rare rebuild vs removed-t mask.
__global__ __launch_bounds__(1024)
void knn_kernel(const float* __restrict__ x, int* __restrict__ idx_out){
  __shared__ float4 spts[NPTS];           // (x,y,z,0.5*xx) 64KB
  int b  = blockIdx.x >> 8;
  int r0 = (blockIdx.x & 255) << 4;
  const float* xb = x + (size_t)b*NPTS*3;
  for (int t = threadIdx.x; t < NPTS; t += 1024){
    float px = xb[t*3+0], py = xb[t*3+1], pz = xb[t*3+2];
    spts[t] = make_float4(px, py, pz, 0.5f*(px*px + py*py + pz*pz));
  }
  __syncthreads();
  int wave = threadIdx.x >> 6, lane = threadIdx.x & 63;
  int i = r0 + wave;
  float4 pi = spts[i];
  float b1 = -INFINITY, b2 = -INFINITY, b3 = -INFINITY;
  int   i1 = 0, i2 = 0, i3 = 0;
  #pragma unroll 8
  for (int t = 0; t < 64; ++t){
    int j = (t << 6) + lane;
    float4 q = spts[j];
    float d = fmaf(pi.z, q.z, fmaf(pi.y, q.y, fmaf(pi.x, q.x, -pi.w))) - q.w;
    bool c1 = d > b1, c2 = d > b2, c3 = d > b3;
    float t2 = __builtin_amdgcn_fmed3f(d, b1, b2);
    float t3 = __builtin_amdgcn_fmed3f(d, b2, b3);
    i3 = c2 ? i2 : (c3 ? j : i3);
    i2 = c1 ? i1 : (c2 ? j : i2);
    i1 = c1 ? j : i1;
    b1 = fmaxf(b1, d);
    b2 = t2; b3 = t3;
  }
  unsigned long long rem = 0ull;          // removed candidate t-bits (per lane)
  size_t obase = ((size_t)b*NPTS + i)*KNB;
  #pragma unroll 1
  for (int kk = 0; kk < KNB; ++kk){
    unsigned s = __float_as_uint(b1);
    unsigned key = s ^ ((unsigned)(((int)s) >> 31) | 0x80000000u);
    key = (key & 0xFFFFFFC0u) | (unsigned)lane;    // lane in low bits
    unsigned bv = key;
    #pragma unroll
    for (int m = 1; m <= 32; m <<= 1){
      unsigned ov = (unsigned)__shfl_xor((int)bv, m);
      bv = bv > ov ? bv : ov;
    }
    int wl = (int)(bv & 63u);
    int bj = __shfl(i1, wl);
    if (lane == 0) idx_out[obase + kk] = bj;
    bool iw = (lane == wl);                         // exactly one lane
    unsigned long long nbit = 1ull << (i1 >> 6);
    rem |= iw ? nbit : 0ull;
    b1 = iw ? b2 : b1;  i1 = iw ? i2 : i1;
    b2 = iw ? b3 : b2;  i2 = iw ? i3 : i2;
    b3 = iw ? -INFINITY : b3;
    if (kk < KNB-1 && __any(b1 == -INFINITY)){
      if (b1 == -INFINITY){               // rare: rebuild top-3 from LDS
        b2 = -INFINITY; b3 = -INFINITY; i1 = 0; i2 = 0; i3 = 0;
        #pragma unroll 8
        for (int t = 0; t < 64; ++t){
          if (rem & (1ull << t)) continue;
          int j = (t << 6) + lane;
          float4 q = spts[j];
          float d = fmaf(pi.z, q.z, fmaf(pi.y, q.y, fmaf(pi.x, q.x, -pi.w))) - q.w;
          bool c1 = d > b1, c2 = d > b2, c3 = d > b3;
          float t2 = __builtin_amdgcn_fmed3f(d, b1, b2);
          float t3 = __builtin_amdgcn_fmed3f(d, b2, b3);
          i3 = c2 ? i2 : (c3 ? j : i3);
          i2 = c1 ? i1 : (c2 ? j : i2);
          i1 = c1 ? j : i1;
          b1 = fmaxf(b1, d);
          b2 = t2; b3 = t3;
        }
      }
    }
  }
}

// ---------------- weight prep ----------------
__global__ __launch_bounds__(256)
void prep_kernel(const float* __restrict__ W2, const float* __restrict__ W3,
                 const float* __restrict__ W4,
                 _Float16* __restrict__ W2T, _Float16* __restrict__ W3T,
                 _Float16* __restrict__ W4T){
  int t = blockIdx.x*256 + threadIdx.x;
  if (t < 4096){ int o=t>>6, k=t&63;                W2T[t] = (_Float16)W2[k*64+o]; }
  else if (t < 12288){ int u=t-4096;  int o=u>>6, k=u&63;   W3T[u] = (_Float16)W3[k*128+o]; }
  else if (t < 45056){ int u=t-12288; int o=u>>7, k=u&127;  W4T[u] = (_Float16)W4[k*256+o]; }
}

__global__ __launch_bounds__(256)
void prep5_kernel(const float* __restrict__ W5, _Float16* __restrict__ W5T){
  __shared__ float tile[32][33];
  int tk = (blockIdx.x & 15) << 5;
  int to = (blockIdx.x >> 4) << 5;
  int lr = threadIdx.x >> 5;
  int lc = threadIdx.x & 31;
  #pragma unroll
  for (int r = 0; r < 32; r += 8)
    tile[lr + r][lc] = W5[(size_t)(tk + lr + r)*1024 + to + lc];
  __syncthreads();
  #pragma unroll
  for (int r = 0; r < 32; r += 8)
    W5T[(size_t)(to + lr + r)*512 + tk + lc] = (_Float16)tile[lc][lr + r];
}

// ---------------- fused edge layers 1-4, packed-f16 epilogues (r10) ----------------
__device__ __forceinline__ void pk_bucket(int mt, bool c1, bool c2, bool c3, half2v m,
                                          half2v& q0, half2v& q1, half2v& q2, half2v& q3){
  const half2v NI = {(_Float16)-INFINITY, (_Float16)-INFINITY};
  if (mt == 0)      q0 = pkmax(q0, m);
  else if (mt == 4) q3 = pkmax(q3, m);
  else if (mt == 1){ q1 = pkmax(q1, c1 ? m : NI); q0 = pkmax(q0, c1 ? NI : m); }
  else if (mt == 2){ q2 = pkmax(q2, c2 ? m : NI); q1 = pkmax(q1, c2 ? NI : m); }
  else             { q3 = pkmax(q3, c3 ? m : NI); q2 = pkmax(q2, c3 ? NI : m); }
}

__device__ __forceinline__ void reduce_write_pk(half2v q0, half2v q1, half2v q2, half2v q3,
                                                _Float16* __restrict__ hc, size_t gp0,
                                                int off, int g, int c){
  q0 = pkmax(q0, shflx_h2(q0,16)); q0 = pkmax(q0, shflx_h2(q0,32));
  q1 = pkmax(q1, shflx_h2(q1,16)); q1 = pkmax(q1, shflx_h2(q1,32));
  q2 = pkmax(q2, shflx_h2(q2,16)); q2 = pkmax(q2, shflx_h2(q2,32));
  q3 = pkmax(q3, shflx_h2(q3,16)); q3 = pkmax(q3, shflx_h2(q3,32));
  half2v v = (g == 0) ? q0 : (g == 1) ? q1 : (g == 2) ? q2 : q3;
  _Float16 r = v.x > v.y ? v.x : v.y;
  hc[(gp0 + g)*512 + off + c] = r;
}

__global__ __launch_bounds__(256)
void edge_kernel(const float* __restrict__ x, const int* __restrict__ knn,
                 const float* __restrict__ W1, const float* __restrict__ g1, const float* __restrict__ b1,
                 const _Float16* __restrict__ W2T, const float* __restrict__ g2, const float* __restrict__ b2,
                 const _Float16* __restrict__ W3T, const float* __restrict__ g3, const float* __restrict__ b3,
                 const _Float16* __restrict__ W4T, const float* __restrict__ g4, const float* __restrict__ b4,
                 _Float16* __restrict__ hc){
  __shared__ __align__(16) char smem[40960];
  _Float16* hb1 = (_Float16*)(smem);             // 80*64*2  = 10240
  _Float16* hb2 = (_Float16*)(smem + 10240);     // 80*64*2  = 10240
  _Float16* hb3 = (_Float16*)(smem + 20480);     // 80*128*2 = 20480
  float*    h0f = (float*)(smem + 20480);        // aliases hb3 head (dead before hb3 written)
  float*    h0c = (float*)(smem + 20480 + 1280);
  const float rs = 1.f / sqrtf(1.f + EPSB);
  const half2v NI = {(_Float16)-INFINITY, (_Float16)-INFINITY};
  int gp0 = blockIdx.x << 2;
  int b   = gp0 >> 12;
  int n0  = gp0 & (NPTS-1);
  const float* xb = x + (size_t)b*NPTS*3;
  int tid = threadIdx.x;
  if (tid < 80){
    int p = tid / 20, k = tid % 20;
    int nb = knn[((size_t)b*NPTS + n0 + p)*KNB + k];
    h0f[tid*4+0] = xb[nb*3+0];
    h0f[tid*4+1] = xb[nb*3+1];
    h0f[tid*4+2] = xb[nb*3+2];
  } else if (tid < 96){
    int u = tid - 80; int p = u >> 2, c = u & 3;
    if (c < 3) h0c[p*4+c] = xb[(n0+p)*3+c];
  }
  __syncthreads();
  int w = tid >> 6, lane = tid & 63, g = lane >> 4, cc = lane & 15;
  bool c1 = (g >= 1), c2 = (g >= 2), c3 = (g >= 3);
  // ---- layer 1: f32 VALU (K=6) ----
  {
    int col = lane;
    float sc = g1[col]*rs, bs = b1[col];
    float w0=W1[col], w1_=W1[64+col], w2_=W1[128+col], w3_=W1[192+col], w4_=W1[256+col], w5_=W1[320+col];
    float cx = h0c[w*4+0], cy = h0c[w*4+1], cz = h0c[w*4+2];
    float m1 = -INFINITY;
    #pragma unroll 5
    for (int k = 0; k < KNB; ++k){
      int r = w*20 + k;
      float a = h0f[r*4+0]*w0 + h0f[r*4+1]*w1_ + h0f[r*4+2]*w2_ + cx*w3_ + cy*w4_ + cz*w5_;
      float vv = a*sc + bs; vv = vv > 0.f ? vv : 0.2f*vv;
      hb1[((r<<6)+col) ^ ((r&7)<<3)] = (_Float16)vv;
      m1 = fmaxf(m1, vv);
    }
    hc[(size_t)(gp0 + w)*512 + col] = (_Float16)m1;
  }
  __syncthreads();
  // ---- layer 2: [80,64]@[64,64]; wave w owns cols w*16..+16 ----
  {
    int colg = (w<<4) + cc;
    float scf = g2[colg]*rs, bsf = b2[colg];
    half2v sc2 = {(_Float16)scf,(_Float16)scf}, bs2 = {(_Float16)bsf,(_Float16)bsf};
    half8 bf0 = loadB_g(W2T, 64, w, 0, lane);
    half8 bf1 = loadB_g(W2T, 64, w, 1, lane);
    half2v q0=NI, q1=NI, q2=NI, q3=NI;
    #pragma unroll
    for (int mt = 0; mt < 5; ++mt){
      f32x4 a = {0.f,0.f,0.f,0.f};
      a = mfma16(loadA_lds(hb1,64,mt,0,lane), bf0, a);
      a = mfma16(loadA_lds(hb1,64,mt,1,lane), bf1, a);
      half2v lo = ep_pk(a[0], a[1], sc2, bs2);
      half2v hi = ep_pk(a[2], a[3], sc2, bs2);
      int r0_ = mt*16 + g*4;
      hb2[((r0_+0)*64+colg) ^ (((r0_+0)&7)<<3)] = lo.x;
      hb2[((r0_+1)*64+colg) ^ (((r0_+1)&7)<<3)] = lo.y;
      hb2[((r0_+2)*64+colg) ^ (((r0_+2)&7)<<3)] = hi.x;
      hb2[((r0_+3)*64+colg) ^ (((r0_+3)&7)<<3)] = hi.y;
      pk_bucket(mt, c1, c2, c3, pkmax(lo,hi), q0, q1, q2, q3);
    }
    reduce_write_pk(q0,q1,q2,q3, hc, gp0, 64 + (w<<4), g, cc);
  }
  __syncthreads();
  // ---- layer 3: [80,64]@[64,128]; wave w owns ntiles 2w,2w+1; A reused ----
  {
    int ntA = (w<<1), ntB = ntA + 1;
    int colA = (ntA<<4) + cc, colB = (ntB<<4) + cc;
    float sAf = g3[colA]*rs, bAf = b3[colA];
    float sBf = g3[colB]*rs, bBf = b3[colB];
    half2v scA2={(_Float16)sAf,(_Float16)sAf}, bsA2={(_Float16)bAf,(_Float16)bAf};
    half2v scB2={(_Float16)sBf,(_Float16)sBf}, bsB2={(_Float16)bBf,(_Float16)bBf};
    half8 bA0 = loadB_g(W3T, 64, ntA, 0, lane);
    half8 bA1 = loadB_g(W3T, 64, ntA, 1, lane);
    half8 bB0 = loadB_g(W3T, 64, ntB, 0, lane);
    half8 bB1 = loadB_g(W3T, 64, ntB, 1, lane);
    half2v qA0=NI,qA1=NI,qA2=NI,qA3=NI, qB0=NI,qB1=NI,qB2=NI,qB3=NI;
    #pragma unroll
    for (int mt = 0; mt < 5; ++mt){
      half8 a0 = loadA_lds(hb2,64,mt,0,lane);
      half8 a1 = loadA_lds(hb2,64,mt,1,lane);
      f32x4 aA = {0.f,0.f,0.f,0.f};
      aA = mfma16(a0, bA0, aA); aA = mfma16(a1, bA1, aA);
      f32x4 aB = {0.f,0.f,0.f,0.f};
      aB = mfma16(a0, bB0, aB); aB = mfma16(a1, bB1, aB);
      half2v loA = ep_pk(aA[0],aA[1],scA2,bsA2);
      half2v hiA = ep_pk(aA[2],aA[3],scA2,bsA2);
      half2v loB = ep_pk(aB[0],aB[1],scB2,bsB2);
      half2v hiB = ep_pk(aB[2],aB[3],scB2,bsB2);
      int r0_ = mt*16 + g*4;
      hb3[((r0_+0)*128+colA) ^ (((r0_+0)&7)<<3)] = loA.x;
      hb3[((r0_+1)*128+colA) ^ (((r0_+1)&7)<<3)] = loA.y;
      hb3[((r0_+2)*128+colA) ^ (((r0_+2)&7)<<3)] = hiA.x;
      hb3[((r0_+3)*128+colA) ^ (((r0_+3)&7)<<3)] = hiA.y;
      hb3[((r0_+0)*128+colB) ^ (((r0_+0)&7)<<3)] = loB.x;
      hb3[((r0_+1)*128+colB) ^ (((r0_+1)&7)<<3)] = loB.y;
      hb3[((r0_+2)*128+colB) ^ (((r0_+2)&7)<<3)] = hiB.x;
      hb3[((r0_+3)*128+colB) ^ (((r0_+3)&7)<<3)] = hiB.y;
      pk_bucket(mt, c1, c2, c3, pkmax(loA,hiA), qA0,qA1,qA2,qA3);
      pk_bucket(mt, c1, c2, c3, pkmax(loB,hiB), qB0,qB1,qB2,qB3);
    }
    reduce_write_pk(qA0,qA1,qA2,qA3, hc, gp0, 128 + (ntA<<4), g, cc);
    reduce_write_pk(qB0,qB1,qB2,qB3, hc, gp0, 128 + (ntB<<4), g, cc);
  }
  __syncthreads();
  // ---- layer 4: [80,128]@[128,256]; pure reg output ----
  #pragma unroll 1
  for (int pass = 0; pass < 2; ++pass){
    int ntA = (pass<<3) + w, ntB = ntA + 4;
    int colA = (ntA<<4) + cc, colB = (ntB<<4) + cc;
    float sAf = g4[colA]*rs, bAf = b4[colA];
    float sBf = g4[colB]*rs, bBf = b4[colB];
    half2v scA2={(_Float16)sAf,(_Float16)sAf}, bsA2={(_Float16)bAf,(_Float16)bAf};
    half2v scB2={(_Float16)sBf,(_Float16)sBf}, bsB2={(_Float16)bBf,(_Float16)bBf};
    half8 bwA[4], bwB[4];
    #pragma unroll
    for (int ks = 0; ks < 4; ++ks){
      bwA[ks] = loadB_g(W4T, 128, ntA, ks, lane);
      bwB[ks] = loadB_g(W4T, 128, ntB, ks, lane);
    }
    half2v qA0=NI,qA1=NI,qA2=NI,qA3=NI, qB0=NI,qB1=NI,qB2=NI,qB3=NI;
    #pragma unroll
    for (int mt = 0; mt < 5; ++mt){
      half8 a[4];
      #pragma unroll
      for (int ks = 0; ks < 4; ++ks) a[ks] = loadA_lds(hb3,128,mt,ks,lane);
      f32x4 aA = {0.f,0.f,0.f,0.f};
      #pragma unroll
      for (int ks = 0; ks < 4; ++ks) aA = mfma16(a[ks], bwA[ks], aA);
      f32x4 aB = {0.f,0.f,0.f,0.f};
      #pragma unroll
      for (int ks = 0; ks < 4; ++ks) aB = mfma16(a[ks], bwB[ks], aB);
      half2v mA = pkmax(ep_pk(aA[0],aA[1],scA2,bsA2), ep_pk(aA[2],aA[3],scA2,bsA2));
      half2v mB = pkmax(ep_pk(aB[0],aB[1],scB2,bsB2), ep_pk(aB[2],aB[3],scB2,bsB2));
      pk_bucket(mt, c1, c2, c3, mA, qA0,qA1,qA2,qA3);
      pk_bucket(mt, c1, c2, c3, mB, qB0,qB1,qB2,qB3);
    }
    reduce_write_pk(qA0,qA1,qA2,qA3, hc, gp0, 256 + (ntA<<4), g, cc);
    reduce_write_pk(qB0,qB1,qB2,qB3, hc, gp0, 256 + (ntB<<4), g, cc);
  }
}

// ---------------- layer 5 GEMM + pooling partials ----------------
__global__ __launch_bounds__(256)
void gemm5_kernel(const _Float16* __restrict__ hc, const _Float16* __restrict__ W5T,
                  const float* __restrict__ g5, const float* __restrict__ b5,
                  float* __restrict__ red){
  __shared__ __align__(16) _Float16 sA[64*512];   // 64KB
  int rowblk = blockIdx.x >> 2;
  int colblk = blockIdx.x & 3;
  int row0 = rowblk << 6;
  #pragma unroll 1
  for (int it = 0; it < 16; ++it){
    int eoff = it*2048 + threadIdx.x*8;
    int row = eoff >> 9;
    int ine = eoff & 511;
    half8 vsrc = *reinterpret_cast<const half8*>(
        &hc[(size_t)(row0 + row)*512 + (ine ^ ((row & 7) << 3))]);
    *reinterpret_cast<half8*>(&sA[(row << 9) + ine]) = vsrc;
  }
  __syncthreads();
  int wave = threadIdx.x >> 6, lane = threadIdx.x & 63;
  f32x4 acc[4][4] = {};
  #pragma unroll 1
  for (int ks = 0; ks < 16; ++ks){
    half8 af[4];
    #pragma unroll
    for (int mt = 0; mt < 4; ++mt) af[mt] = loadA_lds(sA, 512, mt, ks, lane);
    #pragma unroll
    for (int nt = 0; nt < 4; ++nt){
      int ntg = (colblk<<4) + (wave<<2) + nt;
      half8 bf = loadB_g(W5T, 512, ntg, ks, lane);
      #pragma unroll
      for (int mt = 0; mt < 4; ++mt)
        acc[mt][nt] = mfma16(af[mt], bf, acc[mt][nt]);
    }
  }
  int batch = row0 >> 12;
  int chunk = (row0 & (NPTS-1)) >> 6;
  const float rs = 1.f/sqrtf(1.f+EPSB);
  #pragma unroll
  for (int nt = 0; nt < 4; ++nt){
    int ntg = (colblk<<4) + (wave<<2) + nt;
    int colg = (ntg<<4) + (lane & 15);
    float sc = g5[colg]*rs, bs = b5[colg];
    float vmax = -INFINITY, vsum = 0.f;
    #pragma unroll
    for (int mt = 0; mt < 4; ++mt){
      #pragma unroll
      for (int r = 0; r < 4; ++r){
        float vv = acc[mt][nt][r]*sc + bs;
        vv = vv>0.f ? vv : 0.2f*vv;
        vmax = fmaxf(vmax, vv); vsum += vv;
      }
    }
    vmax = fmaxf(vmax, __shfl_xor(vmax, 16)); vsum += __shfl_xor(vsum, 16);
    vmax = fmaxf(vmax, __shfl_xor(vmax, 32)); vsum += __shfl_xor(vsum, 32);
    if ((lane >> 4) == 0){
      size_t base = (size_t)((batch<<6) + chunk)*2048;
      red[base + colg] = vmax;
      red[base + 1024 + colg] = vsum;
    }
  }
}

__global__ __launch_bounds__(256)
void reduce_g_kernel(const float* __restrict__ red, float* __restrict__ g){
  int t = blockIdx.x*256 + threadIdx.x;   // 8192
  int b = t >> 10, col = t & 1023;
  float m = -INFINITY, s = 0.f;
  #pragma unroll 4
  for (int c = 0; c < 64; ++c){
    size_t base = (size_t)((b<<6)+c)*2048;
    m = fmaxf(m, red[base + col]);
    s += red[base + 1024 + col];
  }
  g[(b<<11) + col]        = m;
  g[(b<<11) + 1024 + col] = s * (1.f/4096.f);
}

// ---------------- head MLP: split-K, coalesced o-major loads ----------------
__global__ __launch_bounds__(256)
void fc1_kernel(const float* __restrict__ g, const float* __restrict__ L1,
                const float* __restrict__ g6, const float* __restrict__ b6,
                float* __restrict__ f1){
  __shared__ float part[4][64];
  int b  = blockIdx.x >> 3;
  int og = blockIdx.x & 7;
  int o  = (og << 6) + (threadIdx.x & 63);
  int kg = threadIdx.x >> 6;
  const float* gb = g + (b << 11);
  float acc = 0.f;
  #pragma unroll 8
  for (int k = kg*512; k < kg*512 + 512; ++k) acc += gb[k]*L1[k*512 + o];
  part[kg][threadIdx.x & 63] = acc;
  __syncthreads();
  if (threadIdx.x < 64){
    float s = part[0][threadIdx.x] + part[1][threadIdx.x] + part[2][threadIdx.x] + part[3][threadIdx.x];
    float v = s*(g6[o]/sqrtf(1.f+EPSB)) + b6[o];
    f1[(b<<9) + o] = v > 0.f ? v : 0.2f*v;
  }
}

__global__ __launch_bounds__(256)
void fc2_kernel(const float* __restrict__ f1, const float* __restrict__ L2, const float* __restrict__ L2b,
                const float* __restrict__ g7, const float* __restrict__ b7, float* __restrict__ f2){
  __shared__ float part[4][64];
  int b  = blockIdx.x >> 2;
  int og = blockIdx.x & 3;
  int o  = (og << 6) + (threadIdx.x & 63);
  int kg = threadIdx.x >> 6;
  const float* fb = f1 + (b << 9);
  float acc = 0.f;
  #pragma unroll 8
  for (int k = kg*128; k < kg*128 + 128; ++k) acc += fb[k]*L2[k*256 + o];
  part[kg][threadIdx.x & 63] = acc;
  __syncthreads();
  if (threadIdx.x < 64){
    float s = part[0][threadIdx.x] + part[1][threadIdx.x] + part[2][threadIdx.x] + part[3][threadIdx.x];
    float v = (s + L2b[o])*(g7[o]/sqrtf(1.f+EPSB)) + b7[o];
    f2[(b<<8) + o] = v > 0.f ? v : 0.2f*v;
  }
}

__global__ __launch_bounds__(256)
void fc3_kernel(const float* __restrict__ f2, const float* __restrict__ L3, const float* __restrict__ L3b,
                float* __restrict__ out){
  __shared__ float part[2][128];
  int b  = blockIdx.x;
  int o  = threadIdx.x & 127;
  int kg = threadIdx.x >> 7;
  const float* fb = f2 + (b << 8);
  float acc = 0.f;
  #pragma unroll 8
  for (int k = kg*128; k < kg*128 + 128; ++k) acc += fb[k]*L3[k*128 + o];
  part[kg][o] = acc;
  __syncthreads();
  if (threadIdx.x < 128)
    out[(b<<7) + o] = part[0][o] + part[1][o] + L3b[o];
}

extern "C" void kernel_launch(void* const* d_in, const int* in_sizes, int n_in,
                              void* d_out, int out_size, void* d_ws, size_t ws_size,
                              hipStream_t stream){
  const float* x  = (const float*)d_in[0];
  const float* W1 = (const float*)d_in[1];
  const float* g1 = (const float*)d_in[2];  const float* b1 = (const float*)d_in[3];
  const float* W2 = (const float*)d_in[4];
  const float* g2 = (const float*)d_in[5];  const float* b2 = (const float*)d_in[6];
  const float* W3 = (const float*)d_in[7];
  const float* g3 = (const float*)d_in[8];  const float* b3 = (const float*)d_in[9];
  const float* W4 = (const float*)d_in[10];
  const float* g4 = (const float*)d_in[11]; const float* b4 = (const float*)d_in[12];
  const float* W5 = (const float*)d_in[13];
  const float* g5 = (const float*)d_in[14]; const float* b5 = (const float*)d_in[15];
  const float* L1 = (const float*)d_in[16];
  const float* g6 = (const float*)d_in[17]; const float* b6 = (const float*)d_in[18];
  const float* L2 = (const float*)d_in[19]; const float* L2b = (const float*)d_in[20];
  const float* g7 = (const float*)d_in[21]; const float* b7 = (const float*)d_in[22];
  const float* L3 = (const float*)d_in[23]; const float* L3b = (const float*)d_in[24];

  char* ws = (char*)d_ws;
  int*      idx  = (int*)(ws + 0);                 // 2,621,440 B
  _Float16* hc   = (_Float16*)(ws + 2621440);      // 33,554,432 B
  _Float16* W2T  = (_Float16*)(ws + 36175872);     // 8,192 B
  _Float16* W3T  = (_Float16*)(ws + 36184064);     // 16,384 B
  _Float16* W4T  = (_Float16*)(ws + 36200448);     // 65,536 B
  _Float16* W5T  = (_Float16*)(ws + 36265984);     // 1,048,576 B
  float*    red  = (float*)(ws + 37314560);        // 4,194,304 B
  float*    gbuf = (float*)(ws + 41508864);        // 65,536 B
  float*    f1   = (float*)(ws + 41574400);        // 16,384 B
  float*    f2   = (float*)(ws + 41590784);        // 8,192 B

  knn_kernel<<<2048, 1024, 0, stream>>>(x, idx);
  prep_kernel<<<176, 256, 0, stream>>>(W2, W3, W4, W2T, W3T, W4T);
  prep5_kernel<<<512, 256, 0, stream>>>(W5, W5T);
  edge_kernel<<<8192, 256, 0, stream>>>(x, idx, W1, g1, b1, W2T, g2, b2,
                                        W3T, g3, b3, W4T, g4, b4, hc);
  gemm5_kernel<<<2048, 256, 0, stream>>>(hc, W5T, g5, b5, red);
  reduce_g_kernel<<<32, 256, 0, stream>>>(red, gbuf);
  fc1_kernel<<<64, 256, 0, stream>>>(gbuf, L1, g6, b6, f1);
  fc2_kernel<<<32, 256, 0, stream>>>(f1, L2, L2b, g7, b7, f2);
  fc3_kernel<<<8, 256, 0, stream>>>(f2, L3, L3b, (float*)d_out);
}